// Round 20
// baseline (239.326 us; speedup 1.0000x reference)
//
#include <hip/hip_runtime.h>
#include <cstdint>

#define RFL(x) __builtin_amdgcn_readfirstlane(x)

// ---------------- problem constants ----------------
static constexpr int B  = 512;
static constexpr int C0 = 4,  H0 = 84, W0 = 84;
static constexpr int C1 = 32, H1 = 20, W1 = 20, P1 = H1 * W1;  // 400
static constexpr int C2 = 64, H2 = 9,  W2 = 9,  P2 = H2 * W2;  // 81
static constexpr int C3 = 64, H3 = 7,  W3 = 7,  P3 = H3 * W3;  // 49
static constexpr int K  = C3 * P3;   // 3136
static constexpr int O  = 512;
static constexpr int NJOB2 = B * P2;                 // 41472

// ---------------- workspace layout (bytes) ----------------
static constexpr size_t OFF_S1   = 0;                          // 6,553,600
static constexpr size_t OFF_S2   = 6553600;                    // +2,654,208
static constexpr size_t OFF_S3   = OFF_S2 + 2654208;           // +1,605,632
static constexpr size_t OFF_W2T  = OFF_S3 + 1605632;           // +131,072 +256 zero row
static constexpr size_t OFF_W3T  = OFF_W2T + 131072 + 256;
static constexpr size_t OFF_FW1T = OFF_W3T + 147456;           // +6,422,528
static constexpr size_t OFF_W1T  = OFF_FW1T + 6422528;         // +32,768
static constexpr size_t OFF_CNT  = OFF_W1T + 32768;            // 41472*32
static constexpr size_t OFF_EVT  = OFF_CNT + (size_t)NJOB2 * 32;  // 41472*1152
static constexpr size_t WS_NEEDED = OFF_EVT + (size_t)NJOB2 * 1152;

// ---------------- merged small weight preps (one kernel, range dispatch) ----
// w1T: [o8(4)][ic(4)][ky(8)][o(8)][kx(8)]  (ic stride 512, o8 stride 2048)
__global__ void k_prep_all(const float* __restrict__ w1, float* __restrict__ w1T,
                           const float* __restrict__ w2, float* __restrict__ w2T,
                           const float* __restrict__ w3, float* __restrict__ w3T) {
    int n = blockIdx.x * 256 + threadIdx.x;
    if (n < 8192) {
        int kx = n & 7, o = (n >> 3) & 7, ky = (n >> 6) & 7, ic = (n >> 9) & 3, o8 = n >> 11;
        int oc = o8 * 8 + o;
        w1T[n] = w1[((oc * 4 + ic) * 8 + ky) * 8 + kx];
        return;
    }
    n -= 8192;
    if (n < 32768 + 64) {
        if (n >= 32768) { w2T[n] = 0.0f; return; }
        int oc = n >> 9, r = n & 511;
        int ic = r >> 4, ky = (r >> 2) & 3, kx = r & 3;
        w2T[((ky * 4 + kx) * 32 + ic) * 64 + oc] = w2[n];
        return;
    }
    n -= 32768 + 64;
    if (n < 36864) {
        int oc = n / 576, r = n - oc * 576;
        int ic = r / 9, rr = r - ic * 9;
        int ky = rr / 3, kx = rr - ky * 3;
        w3T[((ky * 3 + kx) * 64 + ic) * 64 + oc] = w3[n];
    }
}

// pure [O][K] -> [K][O] transpose, LDS-tiled 64x64, coalesced both sides
__global__ __launch_bounds__(256) void k_prep_fw1(const float* __restrict__ fw1,
                                                  float* __restrict__ fw1T) {
    __shared__ float tile[64][65];
    int ot = blockIdx.x & 7;            // 8 o-tiles
    int it = blockIdx.x >> 3;           // 49 i-tiles
    int tr = threadIdx.x >> 6;          // 0..3
    int tc = threadIdx.x & 63;
    #pragma unroll
    for (int r = 0; r < 16; r++) {
        int ol = r * 4 + tr;
        tile[ol][tc] = fw1[(size_t)(ot * 64 + ol) * K + it * 64 + tc];
    }
    __syncthreads();
    #pragma unroll
    for (int r = 0; r < 16; r++) {
        int il = r * 4 + tr;
        fw1T[(size_t)(it * 64 + il) * O + ot * 64 + tc] = tile[tc][il];
    }
}

// ---------------- conv1 (dense) + LIF1 -> class bit-planes ----------------
// ic-SPLIT x2 + o8 dispatch interleave:
//  * thread = (o8, ic-half, 2 pixels, 8 oc); 12800 waves (2x r14 TLP) with
//    IDENTICAL total x traffic (each thread reads only its 2 ics).
//  * o8 = blk&3: the 4 blocks sharing an image dispatch adjacently -> L2-hot x.
//  * ih = tid>>7 is wave-uniform -> weight base provably scalar (s_load path).
//  * partials merged via 8 KB LDS reduce; chain order (b1+ic01)+(ic23) --
//    same reorder class as the passing class-trick/event-list transforms.
__global__ __launch_bounds__(256) void k_conv1(const float* __restrict__ x,
                                               const float* __restrict__ w1T,
                                               const float* __restrict__ b1,
                                               uint8_t* __restrict__ s1c) {
    __shared__ float red[128][16];           // 8 KB
    int blk = blockIdx.x;                    // 0..3199
    int o8  = blk & 3;                       // scalar (interleaved)
    int grp = blk >> 2;                      // 0..799
    int tid = threadIdx.x;
    int ih  = tid >> 7;                      // wave-uniform ic-half
    int jl  = tid & 127;
    int job = grp * 128 + jl;                // 0..102399
    int img = job / 200, pair = job - img * 200;
    int oy  = pair / 10;
    int ox0 = (pair - oy * 10) * 2;
    const float* xb = x + (size_t)img * 28224 + (size_t)(ih * 2) * 7056
                        + (size_t)(oy * 4) * W0 + ox0 * 4;
    const float* wh = w1T + o8 * 2048 + ih * 1024;   // scalar base -> s_load

    float acc[2][8];
    #pragma unroll
    for (int pp = 0; pp < 2; pp++)
        #pragma unroll
        for (int o = 0; o < 8; o++) acc[pp][o] = ih ? 0.f : b1[o8 * 8 + o];

    #pragma unroll 1
    for (int it = 0; it < 16; it++) {        // 2 ics x 8 kys, compact I$-fit body
        const float* rp = xb + (it >> 3) * 7056 + (it & 7) * W0;
        float4 a0 = *(const float4*)rp;
        float4 a1 = *(const float4*)(rp + 4);
        float4 a2 = *(const float4*)(rp + 8);
        float xv[12] = {a0.x, a0.y, a0.z, a0.w, a1.x, a1.y, a1.z, a1.w,
                        a2.x, a2.y, a2.z, a2.w};
        const float* wb = wh + (it >> 3) * 512 + (it & 7) * 64;  // uniform
        #pragma unroll
        for (int o = 0; o < 8; o++) {
            #pragma unroll
            for (int pp = 0; pp < 2; pp++) {
                float s = acc[pp][o];
                #pragma unroll
                for (int kx = 0; kx < 8; kx++)
                    s = fmaf(wb[o * 8 + kx], xv[pp * 4 + kx], s);
                acc[pp][o] = s;
            }
        }
    }

    if (ih) {
        #pragma unroll
        for (int pp = 0; pp < 2; pp++)
            #pragma unroll
            for (int o = 0; o < 8; o++) red[jl][pp * 8 + o] = acc[pp][o];
    }
    __syncthreads();
    if (ih) return;
    #pragma unroll
    for (int pp = 0; pp < 2; pp++)
        #pragma unroll
        for (int o = 0; o < 8; o++) acc[pp][o] += red[jl][pp * 8 + o];

    // LIF (constant drive, hard reset) -> first-spike class planes.
    #pragma unroll
    for (int pp = 0; pp < 2; pp++) {
        uint32_t byc[8] = {0, 0, 0, 0, 0, 0, 0, 0};
        #pragma unroll
        for (int o = 0; o < 8; o++) {
            float h = acc[pp][o], v = 0.f;
            uint32_t mm = 0;
            #pragma unroll
            for (int t = 0; t < 8; t++) {
                v = v + (h - v) * 0.5f;          // exact ref op order
                bool sp = (v >= 1.0f);
                mm |= sp ? (1u << t) : 0u;
                v = sp ? 0.f : v;
            }
            uint32_t fs = mm & (0u - mm);
            #pragma unroll
            for (int c = 0; c < 8; c++) byc[c] |= ((fs >> c) & 1u) << o;
        }
        int pix = oy * W1 + ox0 + pp;
        uint8_t* op = s1c + (size_t)(img * P1 + pix) * 32 + o8;
        #pragma unroll
        for (int c = 0; c < 8; c++) op[c * 4] = (uint8_t)byc[c];
    }
}

// ---------------- event-list prep: 8 threads/job, LDS-staged, coalesced out --
__global__ __launch_bounds__(256) void k_evt(const uint8_t* __restrict__ s1c,
                                             uint32_t* __restrict__ cnt,
                                             uint16_t* __restrict__ evl) {
    __shared__ __align__(16) uint16_t buf[32][576];   // 36,864 B
    int tid = threadIdx.x;
    int jl  = tid >> 3;                              // local job 0..31
    int job = blockIdx.x * 32 + jl;                  // 41472 = 1296*32
    int c   = tid & 7;
    int b = job / P2, pix = job - b * P2;
    int oy = pix / W2, ox = pix - oy * W2;
    const uint8_t* sb = s1c + (size_t)b * P1 * 32 + c * 4;

    int count = 0;
    #pragma unroll
    for (int pos = 0; pos < 16; pos++) {
        int ipix = (oy * 2 + (pos >> 2)) * W1 + ox * 2 + (pos & 3);
        count += __popc(*(const uint32_t*)(sb + (size_t)ipix * 32));
    }
    int padded = (count + 7) & ~7;

    int incl = padded;                               // 8-lane inclusive prefix
    #pragma unroll
    for (int d = 1; d < 8; d <<= 1) {
        int t = __shfl_up(incl, d, 8);
        if ((tid & 7) >= d) incl += t;
    }
    uint16_t* out = &buf[jl][incl - padded];

    int k = 0;
    #pragma unroll 1
    for (int pos = 0; pos < 16; pos++) {
        int ipix = (oy * 2 + (pos >> 2)) * W1 + ox * 2 + (pos & 3);
        uint32_t w = *(const uint32_t*)(sb + (size_t)ipix * 32);
        while (w) {
            int i = __builtin_ctz(w);
            w &= w - 1;
            out[k++] = (uint16_t)((pos << 5) + i);
        }
    }
    while (k < padded) out[k++] = 512;               // zero-row pad (exact +0.0f)
    cnt[job * 8 + c] = (uint32_t)padded;

    __syncthreads();
    const uint4* src = (const uint4*)&buf[0][0];
    uint4* dst = (uint4*)(evl + (size_t)blockIdx.x * 32 * 576);
    #pragma unroll
    for (int i = 0; i < 9; i++) dst[tid + i * 256] = src[tid + i * 256];
}

// ---------------- conv2 + LIF2 (event-list driven) -> t bit-planes --------
__global__ __launch_bounds__(256) void k_conv2_ev(const uint32_t* __restrict__ cnt,
                                                  const uint16_t* __restrict__ evl,
                                                  const float* __restrict__ w2T,
                                                  const float* __restrict__ b2,
                                                  uint8_t* __restrict__ s2p) {
    int wid = RFL(blockIdx.x * 4 + (threadIdx.x >> 6));   // scalar job id
    int lane = threadIdx.x & 63;
    int b = wid / P2, pix = wid - b * P2;
    const uint32_t* evw = (const uint32_t*)(evl + (size_t)wid * 576);
    const uint32_t* cp  = cnt + wid * 8;
    float A[8];
    #pragma unroll
    for (int c = 0; c < 8; c++) A[c] = 0.f;
    int kw = 0;
    #define CLS(c)                                                            \
    {   int n = (int)cp[c];                                                   \
        for (int k = 0; k < n; k += 8) {                                      \
            uint32_t d0 = evw[kw], d1 = evw[kw + 1];                          \
            uint32_t d2 = evw[kw + 2], d3 = evw[kw + 3]; kw += 4;             \
            float v0 = w2T[(d0 & 0xffffu) * 64 + lane];                       \
            float v1 = w2T[(d0 >> 16)    * 64 + lane];                        \
            float v2 = w2T[(d1 & 0xffffu) * 64 + lane];                       \
            float v3 = w2T[(d1 >> 16)    * 64 + lane];                        \
            float v4 = w2T[(d2 & 0xffffu) * 64 + lane];                       \
            float v5 = w2T[(d2 >> 16)    * 64 + lane];                        \
            float v6 = w2T[(d3 & 0xffffu) * 64 + lane];                       \
            float v7 = w2T[(d3 >> 16)    * 64 + lane];                        \
            A[c] += v0; A[c] += v1; A[c] += v2; A[c] += v3;                   \
            A[c] += v4; A[c] += v5; A[c] += v6; A[c] += v7;                   \
        }                                                                     \
    }
    CLS(0) CLS(1) CLS(2) CLS(3) CLS(4) CLS(5) CLS(6) CLS(7)
    #undef CLS

    float y[8];
    y[0] = A[0];
    y[1] = A[0] + A[1];
    y[2] = A[0] + A[2];
    y[3] = A[0] + A[1] + A[3];
    y[4] = A[0] + A[4];
    y[5] = A[0] + A[1] + A[2] + A[5];
    y[6] = A[0] + A[6];
    y[7] = A[0] + A[1] + A[3] + A[7];

    float bo = b2[lane];
    uint32_t mout = 0;
    float v = 0.f;
    #pragma unroll
    for (int t = 0; t < 8; t++) {
        float yt = y[t] + bo;
        v = v + (yt - v) * 0.5f;
        bool sp = (v >= 1.0f);
        mout |= sp ? (1u << t) : 0u;
        v = sp ? 0.f : v;
    }
    unsigned long long* op = (unsigned long long*)(s2p + (size_t)(b * P2 + pix) * 64);
    #pragma unroll
    for (int t = 0; t < 8; t++) {
        unsigned long long bm = __ballot((mout >> t) & 1u);
        if (lane == 0) op[t] = bm;
    }
}

// ---------------- conv2 fallback (round-13 guarded scan) ----------------
__global__ __launch_bounds__(256) void k_conv2_old(const uint8_t* __restrict__ s1c,
                                                   const float* __restrict__ w2T,
                                                   const float* __restrict__ b2,
                                                   uint8_t* __restrict__ s2p) {
    int wid = blockIdx.x * 4 + (threadIdx.x >> 6);
    int lane = threadIdx.x & 63;
    int b = wid / P2, pix = wid - b * P2;
    int oy = pix / W2, ox = pix - oy * W2;
    float A[8];
    #pragma unroll
    for (int c = 0; c < 8; c++) A[c] = 0.f;
    #pragma unroll
    for (int ky = 0; ky < 4; ky++) {
        #pragma unroll
        for (int kx = 0; kx < 4; kx++) {
            int mofs = RFL((b * P1 + (oy * 2 + ky) * W1 + (ox * 2 + kx)) * 32);
            const uint32_t* mp = (const uint32_t*)(s1c + mofs);
            const float* wp = w2T + (ky * 4 + kx) * 32 * 64 + lane;
            uint32_t w0 = mp[0], w1 = mp[1], w2 = mp[2], w3 = mp[3];
            uint32_t w4 = mp[4], w5 = mp[5], w6 = mp[6], w7 = mp[7];
            while (w0 | w1 | w2 | w3 | w4 | w5 | w6 | w7) {
                if (w0) { int i = __builtin_ctz(w0); w0 &= w0 - 1; A[0] += wp[i * 64]; }
                if (w1) { int i = __builtin_ctz(w1); w1 &= w1 - 1; A[1] += wp[i * 64]; }
                if (w2) { int i = __builtin_ctz(w2); w2 &= w2 - 1; A[2] += wp[i * 64]; }
                if (w3) { int i = __builtin_ctz(w3); w3 &= w3 - 1; A[3] += wp[i * 64]; }
                if (w4) { int i = __builtin_ctz(w4); w4 &= w4 - 1; A[4] += wp[i * 64]; }
                if (w5) { int i = __builtin_ctz(w5); w5 &= w5 - 1; A[5] += wp[i * 64]; }
                if (w6) { int i = __builtin_ctz(w6); w6 &= w6 - 1; A[6] += wp[i * 64]; }
                if (w7) { int i = __builtin_ctz(w7); w7 &= w7 - 1; A[7] += wp[i * 64]; }
            }
        }
    }
    float y[8];
    y[0] = A[0];
    y[1] = A[0] + A[1];
    y[2] = A[0] + A[2];
    y[3] = A[0] + A[1] + A[3];
    y[4] = A[0] + A[4];
    y[5] = A[0] + A[1] + A[2] + A[5];
    y[6] = A[0] + A[6];
    y[7] = A[0] + A[1] + A[3] + A[7];
    float bo = b2[lane];
    uint32_t mout = 0;
    float v = 0.f;
    #pragma unroll
    for (int t = 0; t < 8; t++) {
        float yt = y[t] + bo;
        v = v + (yt - v) * 0.5f;
        bool sp = (v >= 1.0f);
        mout |= sp ? (1u << t) : 0u;
        v = sp ? 0.f : v;
    }
    unsigned long long* op = (unsigned long long*)(s2p + (size_t)(b * P2 + pix) * 64);
    #pragma unroll
    for (int t = 0; t < 8; t++) {
        unsigned long long bm = __ballot((mout >> t) & 1u);
        if (lane == 0) op[t] = bm;
    }
}

// ---------------- conv3 + LIF3 (guarded 8-chain scan, round-13) ----------
__global__ __launch_bounds__(256) void k_conv3(const uint8_t* __restrict__ s2p,
                                               const float* __restrict__ w3T,
                                               const float* __restrict__ b3,
                                               uint8_t* __restrict__ s3m) {
    int wid = blockIdx.x * 4 + (threadIdx.x >> 6);
    int lane = threadIdx.x & 63;
    int b = wid / P3, pix = wid - b * P3;
    int oy = pix / W3, ox = pix - oy * W3;
    float A[8];
    #pragma unroll
    for (int t = 0; t < 8; t++) A[t] = 0.f;
    #pragma unroll
    for (int ky = 0; ky < 3; ky++) {
        #pragma unroll
        for (int kx = 0; kx < 3; kx++) {
            int mofs = RFL((b * P2 + (oy + ky) * W2 + (ox + kx)) * 64);
            const unsigned long long* mp = (const unsigned long long*)(s2p + mofs);
            const float* wp = w3T + (ky * 3 + kx) * 64 * 64 + lane;
            unsigned long long m0 = mp[0], m1 = mp[1], m2 = mp[2], m3 = mp[3];
            unsigned long long m4 = mp[4], m5 = mp[5], m6 = mp[6], m7 = mp[7];
            while (m0 | m1 | m2 | m3 | m4 | m5 | m6 | m7) {
                if (m0) { int i = __builtin_ctzll(m0); m0 &= m0 - 1; A[0] += wp[i * 64]; }
                if (m1) { int i = __builtin_ctzll(m1); m1 &= m1 - 1; A[1] += wp[i * 64]; }
                if (m2) { int i = __builtin_ctzll(m2); m2 &= m2 - 1; A[2] += wp[i * 64]; }
                if (m3) { int i = __builtin_ctzll(m3); m3 &= m3 - 1; A[3] += wp[i * 64]; }
                if (m4) { int i = __builtin_ctzll(m4); m4 &= m4 - 1; A[4] += wp[i * 64]; }
                if (m5) { int i = __builtin_ctzll(m5); m5 &= m5 - 1; A[5] += wp[i * 64]; }
                if (m6) { int i = __builtin_ctzll(m6); m6 &= m6 - 1; A[6] += wp[i * 64]; }
                if (m7) { int i = __builtin_ctzll(m7); m7 &= m7 - 1; A[7] += wp[i * 64]; }
            }
        }
    }
    float bo = b3[lane];
    uint32_t mout = 0;
    float v = 0.f;
    #pragma unroll
    for (int t = 0; t < 8; t++) {
        float y = A[t] + bo;
        v = v + (y - v) * 0.5f;
        bool sp = (v >= 1.0f);
        mout |= sp ? (1u << t) : 0u;
        v = sp ? 0.f : v;
    }
    s3m[(size_t)(b * P3 + pix) * 64 + lane] = (uint8_t)mout;
}

// ---------------- fc1 + LIF4 + mean + fc2 ----------------
__global__ __launch_bounds__(256) void k_fc(const uint8_t* __restrict__ s3m,
                                            const float* __restrict__ fw1T,
                                            const float* __restrict__ fb1,
                                            const float* __restrict__ fw2,
                                            const float* __restrict__ fb2,
                                            float* __restrict__ out) {
    __shared__ float red[3][64][65];
    int b = blockIdx.x;
    int w = threadIdx.x >> 6;
    int lane = threadIdx.x & 63;
    float acc[8][8];
    #pragma unroll
    for (int j = 0; j < 8; j++)
        #pragma unroll
        for (int t = 0; t < 8; t++) acc[j][t] = 0.f;

    int ibeg = w * 784;
    for (int i0 = ibeg; i0 < ibeg + 784; i0 += 16) {
        int base = RFL(b * K + i0);
        const uint32_t* mp = (const uint32_t*)(s3m + base);
        #pragma unroll
        for (int d = 0; d < 4; d++) {
            uint32_t md = mp[d];
            if (md == 0) continue;
            #pragma unroll
            for (int q = 0; q < 4; q++) {
                uint32_t m = (md >> (q * 8)) & 0xffu;
                if (m == 0) continue;
                int i_our = i0 + d * 4 + q;
                int pix = i_our >> 6, c = i_our & 63;
                const float4* wp = (const float4*)(fw1T + (size_t)(c * 49 + pix) * O + lane * 8);
                float4 wa = wp[0], wb = wp[1];
                float wv[8] = {wa.x, wa.y, wa.z, wa.w, wb.x, wb.y, wb.z, wb.w};
                #pragma unroll
                for (int t = 0; t < 8; t++) {
                    if (m & (1u << t)) {
                        #pragma unroll
                        for (int j = 0; j < 8; j++) acc[j][t] += wv[j];
                    }
                }
            }
        }
    }

    if (w > 0) {
        #pragma unroll
        for (int j = 0; j < 8; j++)
            #pragma unroll
            for (int t = 0; t < 8; t++) red[w - 1][lane][j * 8 + t] = acc[j][t];
    }
    __syncthreads();
    if (w != 0) return;

    #pragma unroll
    for (int ww = 0; ww < 3; ww++)
        #pragma unroll
        for (int j = 0; j < 8; j++)
            #pragma unroll
            for (int t = 0; t < 8; t++) acc[j][t] += red[ww][lane][j * 8 + t];

    float msum[8];
    #pragma unroll
    for (int j = 0; j < 8; j++) {
        float yb = fb1[lane * 8 + j];
        float v = 0.f, cntt = 0.f;
        #pragma unroll
        for (int t = 0; t < 8; t++) {
            float y = acc[j][t] + yb;
            v = v + (y - v) * 0.5f;
            bool sp = (v >= 1.0f);
            cntt += sp ? 1.f : 0.f;
            v = sp ? 0.f : v;
        }
        msum[j] = cntt * 0.125f;
    }
    #pragma unroll
    for (int kk = 0; kk < 6; kk++) {
        const float* wr = fw2 + kk * O + lane * 8;
        float pv = 0.f;
        #pragma unroll
        for (int j = 0; j < 8; j++) pv += msum[j] * wr[j];
        #pragma unroll
        for (int off = 32; off > 0; off >>= 1) pv += __shfl_down(pv, off, 64);
        if (lane == 0) out[b * 6 + kk] = pv + fb2[kk];
    }
}

// ---------------- launch ----------------
extern "C" void kernel_launch(void* const* d_in, const int* in_sizes, int n_in,
                              void* d_out, int out_size, void* d_ws, size_t ws_size,
                              hipStream_t stream) {
    const float* x   = (const float*)d_in[0];
    const float* w1  = (const float*)d_in[1];
    const float* b1  = (const float*)d_in[2];
    const float* w2  = (const float*)d_in[3];
    const float* b2  = (const float*)d_in[4];
    const float* w3  = (const float*)d_in[5];
    const float* b3  = (const float*)d_in[6];
    const float* fw1 = (const float*)d_in[7];
    const float* fb1 = (const float*)d_in[8];
    const float* fw2 = (const float*)d_in[9];
    const float* fb2 = (const float*)d_in[10];
    float* out = (float*)d_out;

    uint8_t*  ws   = (uint8_t*)d_ws;
    uint8_t*  s1c  = ws + OFF_S1;
    uint8_t*  s2p  = ws + OFF_S2;
    uint8_t*  s3m  = ws + OFF_S3;
    float*    w2T  = (float*)(ws + OFF_W2T);
    float*    w3T  = (float*)(ws + OFF_W3T);
    float*    fw1T = (float*)(ws + OFF_FW1T);
    float*    w1T  = (float*)(ws + OFF_W1T);
    uint32_t* cnt  = (uint32_t*)(ws + OFF_CNT);
    uint16_t* evl  = (uint16_t*)(ws + OFF_EVT);

    hipLaunchKernelGGL(k_prep_all, dim3(305),   dim3(256), 0, stream,
                       w1, w1T, w2, w2T, w3, w3T);
    hipLaunchKernelGGL(k_prep_fw1, dim3(392),   dim3(256), 0, stream, fw1, fw1T);
    hipLaunchKernelGGL(k_conv1,    dim3(3200),  dim3(256), 0, stream, x, w1T, b1, s1c);
    if (ws_size >= WS_NEEDED) {
        hipLaunchKernelGGL(k_evt,      dim3(1296),  dim3(256), 0, stream, s1c, cnt, evl);
        hipLaunchKernelGGL(k_conv2_ev, dim3(10368), dim3(256), 0, stream, cnt, evl, w2T, b2, s2p);
    } else {
        hipLaunchKernelGGL(k_conv2_old, dim3(10368), dim3(256), 0, stream, s1c, w2T, b2, s2p);
    }
    hipLaunchKernelGGL(k_conv3,    dim3(6272),  dim3(256), 0, stream, s2p, w3T, b3, s3m);
    hipLaunchKernelGGL(k_fc,       dim3(512),   dim3(256), 0, stream, s3m, fw1T, fb1, fw2, fb2, out);
}

// Round 21
// 168.662 us; speedup vs baseline: 1.4190x; 1.4190x over previous
//
#include <hip/hip_runtime.h>
#include <cstdint>

#define RFL(x) __builtin_amdgcn_readfirstlane(x)

// ---------------- problem constants ----------------
static constexpr int B  = 512;
static constexpr int C0 = 4,  H0 = 84, W0 = 84;
static constexpr int C1 = 32, H1 = 20, W1 = 20, P1 = H1 * W1;  // 400
static constexpr int C2 = 64, H2 = 9,  W2 = 9,  P2 = H2 * W2;  // 81
static constexpr int C3 = 64, H3 = 7,  W3 = 7,  P3 = H3 * W3;  // 49
static constexpr int K  = C3 * P3;   // 3136
static constexpr int O  = 512;
static constexpr int NJOB2 = B * P2;                 // 41472

// ---------------- workspace layout (bytes) ----------------
// s1c: class bit-planes [b][pix][c(8)] u32, bit = oc  (32B per (b,pix))
// s2p: t bit-planes     [b][pix][t(8)] u64            (64B per (b,pix))
// w2T: 512 rows x 64 oc f32 + 64-float ZERO row (row index 512)
// evl: per job 576 u16 slots (class-sorted, each class padded to x8)
static constexpr size_t OFF_S1   = 0;                          // 6,553,600
static constexpr size_t OFF_S2   = 6553600;                    // +2,654,208
static constexpr size_t OFF_S3   = OFF_S2 + 2654208;           // +1,605,632
static constexpr size_t OFF_W2T  = OFF_S3 + 1605632;           // +131,072 +256 zero row
static constexpr size_t OFF_W3T  = OFF_W2T + 131072 + 256;
static constexpr size_t OFF_FW1T = OFF_W3T + 147456;           // +6,422,528
static constexpr size_t OFF_W1T  = OFF_FW1T + 6422528;         // +32,768
static constexpr size_t OFF_CNT  = OFF_W1T + 32768;            // 41472*32
static constexpr size_t OFF_EVT  = OFF_CNT + (size_t)NJOB2 * 32;  // 41472*1152
static constexpr size_t WS_NEEDED = OFF_EVT + (size_t)NJOB2 * 1152;

// ---------------- merged small weight preps (one kernel, range dispatch) ----
// w1T: [o8(4)][ic(4)][ky(8)][o(8)][kx(8)]
__global__ void k_prep_all(const float* __restrict__ w1, float* __restrict__ w1T,
                           const float* __restrict__ w2, float* __restrict__ w2T,
                           const float* __restrict__ w3, float* __restrict__ w3T) {
    int n = blockIdx.x * 256 + threadIdx.x;
    if (n < 8192) {
        int kx = n & 7, o = (n >> 3) & 7, ky = (n >> 6) & 7, ic = (n >> 9) & 3, o8 = n >> 11;
        int oc = o8 * 8 + o;
        w1T[n] = w1[((oc * 4 + ic) * 8 + ky) * 8 + kx];
        return;
    }
    n -= 8192;
    if (n < 32768 + 64) {
        if (n >= 32768) { w2T[n] = 0.0f; return; }
        int oc = n >> 9, r = n & 511;
        int ic = r >> 4, ky = (r >> 2) & 3, kx = r & 3;
        w2T[((ky * 4 + kx) * 32 + ic) * 64 + oc] = w2[n];
        return;
    }
    n -= 32768 + 64;
    if (n < 36864) {
        int oc = n / 576, r = n - oc * 576;
        int ic = r / 9, rr = r - ic * 9;
        int ky = rr / 3, kx = rr - ky * 3;
        w3T[((ky * 3 + kx) * 64 + ic) * 64 + oc] = w3[n];
    }
}

// pure [O][K] -> [K][O] transpose, LDS-tiled 64x64, coalesced both sides
__global__ __launch_bounds__(256) void k_prep_fw1(const float* __restrict__ fw1,
                                                  float* __restrict__ fw1T) {
    __shared__ float tile[64][65];
    int ot = blockIdx.x & 7;            // 8 o-tiles
    int it = blockIdx.x >> 3;           // 49 i-tiles
    int tr = threadIdx.x >> 6;          // 0..3
    int tc = threadIdx.x & 63;
    #pragma unroll
    for (int r = 0; r < 16; r++) {
        int ol = r * 4 + tr;
        tile[ol][tc] = fw1[(size_t)(ot * 64 + ol) * K + it * 64 + tc];
    }
    __syncthreads();
    #pragma unroll
    for (int r = 0; r < 16; r++) {
        int il = r * 4 + tr;
        fw1T[(size_t)(it * 64 + il) * O + ot * 64 + tc] = tile[tc][il];
    }
}

// ---------------- conv1 (dense) + LIF1 -> class bit-planes ----------------
// ROUND-14 BEST (83 us) -- PARKED (7 structural variants all >= 80 us).
__global__ __launch_bounds__(256) void k_conv1(const float* __restrict__ x,
                                               const float* __restrict__ w1T,
                                               const float* __restrict__ b1,
                                               uint8_t* __restrict__ s1c) {
    int blk = blockIdx.x;                    // 0..1599
    int o8  = blk / 400;                     // scalar 0..3
    int rest = (blk - o8 * 400) * 256 + threadIdx.x;   // 0..102399
    int img = rest / 200, pair = rest - img * 200;
    int oy  = pair / 10;
    int ox0 = (pair - oy * 10) * 2;
    const float* xb = x + (size_t)img * 28224 + (size_t)(oy * 4) * W0 + ox0 * 4;
    const float* wh = w1T + o8 * 2048;       // scalar base -> s_load

    float acc[2][8];
    #pragma unroll
    for (int pp = 0; pp < 2; pp++)
        #pragma unroll
        for (int o = 0; o < 8; o++) acc[pp][o] = b1[o8 * 8 + o];

    #pragma unroll 1
    for (int ic = 0; ic < C0; ic++) {
        #pragma unroll 1
        for (int ky = 0; ky < 8; ky++) {
            const float* rp = xb + ic * 7056 + ky * W0;
            float4 a0 = *(const float4*)rp;
            float4 a1 = *(const float4*)(rp + 4);
            float4 a2 = *(const float4*)(rp + 8);
            float xv[12] = {a0.x, a0.y, a0.z, a0.w, a1.x, a1.y, a1.z, a1.w,
                            a2.x, a2.y, a2.z, a2.w};
            const float* wb = wh + (ic * 8 + ky) * 64;   // 64 contiguous, uniform
            #pragma unroll
            for (int o = 0; o < 8; o++) {
                #pragma unroll
                for (int pp = 0; pp < 2; pp++) {
                    float s = acc[pp][o];
                    #pragma unroll
                    for (int kx = 0; kx < 8; kx++)
                        s = fmaf(wb[o * 8 + kx], xv[pp * 4 + kx], s);
                    acc[pp][o] = s;
                }
            }
        }
    }

    #pragma unroll
    for (int pp = 0; pp < 2; pp++) {
        uint32_t byc[8] = {0, 0, 0, 0, 0, 0, 0, 0};
        #pragma unroll
        for (int o = 0; o < 8; o++) {
            float h = acc[pp][o], v = 0.f;
            uint32_t mm = 0;
            #pragma unroll
            for (int t = 0; t < 8; t++) {
                v = v + (h - v) * 0.5f;          // exact ref op order
                bool sp = (v >= 1.0f);
                mm |= sp ? (1u << t) : 0u;
                v = sp ? 0.f : v;
            }
            uint32_t fs = mm & (0u - mm);
            #pragma unroll
            for (int c = 0; c < 8; c++) byc[c] |= ((fs >> c) & 1u) << o;
        }
        int pix = oy * W1 + ox0 + pp;
        uint8_t* op = s1c + (size_t)(img * P1 + pix) * 32 + o8;
        #pragma unroll
        for (int c = 0; c < 8; c++) op[c * 4] = (uint8_t)byc[c];
    }
}

// ---------------- event-list prep: 8 threads/job, LDS-staged, coalesced out --
__global__ __launch_bounds__(256) void k_evt(const uint8_t* __restrict__ s1c,
                                             uint32_t* __restrict__ cnt,
                                             uint16_t* __restrict__ evl) {
    __shared__ __align__(16) uint16_t buf[32][576];   // 36,864 B
    int tid = threadIdx.x;
    int jl  = tid >> 3;                              // local job 0..31
    int job = blockIdx.x * 32 + jl;                  // 41472 = 1296*32
    int c   = tid & 7;
    int b = job / P2, pix = job - b * P2;
    int oy = pix / W2, ox = pix - oy * W2;
    const uint8_t* sb = s1c + (size_t)b * P1 * 32 + c * 4;

    int count = 0;
    #pragma unroll
    for (int pos = 0; pos < 16; pos++) {
        int ipix = (oy * 2 + (pos >> 2)) * W1 + ox * 2 + (pos & 3);
        count += __popc(*(const uint32_t*)(sb + (size_t)ipix * 32));
    }
    int padded = (count + 7) & ~7;

    int incl = padded;                               // 8-lane inclusive prefix
    #pragma unroll
    for (int d = 1; d < 8; d <<= 1) {
        int t = __shfl_up(incl, d, 8);
        if ((tid & 7) >= d) incl += t;
    }
    uint16_t* out = &buf[jl][incl - padded];

    int k = 0;
    #pragma unroll 1
    for (int pos = 0; pos < 16; pos++) {
        int ipix = (oy * 2 + (pos >> 2)) * W1 + ox * 2 + (pos & 3);
        uint32_t w = *(const uint32_t*)(sb + (size_t)ipix * 32);
        while (w) {
            int i = __builtin_ctz(w);
            w &= w - 1;
            out[k++] = (uint16_t)((pos << 5) + i);
        }
    }
    while (k < padded) out[k++] = 512;               // zero-row pad (exact +0.0f)
    cnt[job * 8 + c] = (uint32_t)padded;

    __syncthreads();
    // coalesced copy-out: 32 jobs x 576 u16 = 2304 uint4
    const uint4* src = (const uint4*)&buf[0][0];
    uint4* dst = (uint4*)(evl + (size_t)blockIdx.x * 32 * 576);
    #pragma unroll
    for (int i = 0; i < 9; i++) dst[tid + i * 256] = src[tid + i * 256];
}

// ---------------- conv2 + LIF2 (event-list driven) -> t bit-planes --------
// 8 events/round: 4 scalar event dwords -> 8 independent coalesced weight
// loads in flight -> 8 adds into static A[c].
__global__ __launch_bounds__(256) void k_conv2_ev(const uint32_t* __restrict__ cnt,
                                                  const uint16_t* __restrict__ evl,
                                                  const float* __restrict__ w2T,
                                                  const float* __restrict__ b2,
                                                  uint8_t* __restrict__ s2p) {
    int wid = RFL(blockIdx.x * 4 + (threadIdx.x >> 6));   // scalar job id
    int lane = threadIdx.x & 63;
    int b = wid / P2, pix = wid - b * P2;
    const uint32_t* evw = (const uint32_t*)(evl + (size_t)wid * 576);
    const uint32_t* cp  = cnt + wid * 8;
    float A[8];
    #pragma unroll
    for (int c = 0; c < 8; c++) A[c] = 0.f;
    int kw = 0;
    #define CLS(c)                                                            \
    {   int n = (int)cp[c];                                                   \
        for (int k = 0; k < n; k += 8) {                                      \
            uint32_t d0 = evw[kw], d1 = evw[kw + 1];                          \
            uint32_t d2 = evw[kw + 2], d3 = evw[kw + 3]; kw += 4;             \
            float v0 = w2T[(d0 & 0xffffu) * 64 + lane];                       \
            float v1 = w2T[(d0 >> 16)    * 64 + lane];                        \
            float v2 = w2T[(d1 & 0xffffu) * 64 + lane];                       \
            float v3 = w2T[(d1 >> 16)    * 64 + lane];                        \
            float v4 = w2T[(d2 & 0xffffu) * 64 + lane];                       \
            float v5 = w2T[(d2 >> 16)    * 64 + lane];                        \
            float v6 = w2T[(d3 & 0xffffu) * 64 + lane];                       \
            float v7 = w2T[(d3 >> 16)    * 64 + lane];                        \
            A[c] += v0; A[c] += v1; A[c] += v2; A[c] += v3;                   \
            A[c] += v4; A[c] += v5; A[c] += v6; A[c] += v7;                   \
        }                                                                     \
    }
    CLS(0) CLS(1) CLS(2) CLS(3) CLS(4) CLS(5) CLS(6) CLS(7)
    #undef CLS

    float y[8];
    y[0] = A[0];
    y[1] = A[0] + A[1];
    y[2] = A[0] + A[2];
    y[3] = A[0] + A[1] + A[3];
    y[4] = A[0] + A[4];
    y[5] = A[0] + A[1] + A[2] + A[5];
    y[6] = A[0] + A[6];
    y[7] = A[0] + A[1] + A[3] + A[7];

    float bo = b2[lane];
    uint32_t mout = 0;
    float v = 0.f;
    #pragma unroll
    for (int t = 0; t < 8; t++) {
        float yt = y[t] + bo;
        v = v + (yt - v) * 0.5f;
        bool sp = (v >= 1.0f);
        mout |= sp ? (1u << t) : 0u;
        v = sp ? 0.f : v;
    }
    unsigned long long* op = (unsigned long long*)(s2p + (size_t)(b * P2 + pix) * 64);
    #pragma unroll
    for (int t = 0; t < 8; t++) {
        unsigned long long bm = __ballot((mout >> t) & 1u);
        if (lane == 0) op[t] = bm;
    }
}

// ---------------- conv2 fallback (round-13 guarded scan) ----------------
__global__ __launch_bounds__(256) void k_conv2_old(const uint8_t* __restrict__ s1c,
                                                   const float* __restrict__ w2T,
                                                   const float* __restrict__ b2,
                                                   uint8_t* __restrict__ s2p) {
    int wid = blockIdx.x * 4 + (threadIdx.x >> 6);
    int lane = threadIdx.x & 63;
    int b = wid / P2, pix = wid - b * P2;
    int oy = pix / W2, ox = pix - oy * W2;
    float A[8];
    #pragma unroll
    for (int c = 0; c < 8; c++) A[c] = 0.f;
    #pragma unroll
    for (int ky = 0; ky < 4; ky++) {
        #pragma unroll
        for (int kx = 0; kx < 4; kx++) {
            int mofs = RFL((b * P1 + (oy * 2 + ky) * W1 + (ox * 2 + kx)) * 32);
            const uint32_t* mp = (const uint32_t*)(s1c + mofs);
            const float* wp = w2T + (ky * 4 + kx) * 32 * 64 + lane;
            uint32_t w0 = mp[0], w1 = mp[1], w2 = mp[2], w3 = mp[3];
            uint32_t w4 = mp[4], w5 = mp[5], w6 = mp[6], w7 = mp[7];
            while (w0 | w1 | w2 | w3 | w4 | w5 | w6 | w7) {
                if (w0) { int i = __builtin_ctz(w0); w0 &= w0 - 1; A[0] += wp[i * 64]; }
                if (w1) { int i = __builtin_ctz(w1); w1 &= w1 - 1; A[1] += wp[i * 64]; }
                if (w2) { int i = __builtin_ctz(w2); w2 &= w2 - 1; A[2] += wp[i * 64]; }
                if (w3) { int i = __builtin_ctz(w3); w3 &= w3 - 1; A[3] += wp[i * 64]; }
                if (w4) { int i = __builtin_ctz(w4); w4 &= w4 - 1; A[4] += wp[i * 64]; }
                if (w5) { int i = __builtin_ctz(w5); w5 &= w5 - 1; A[5] += wp[i * 64]; }
                if (w6) { int i = __builtin_ctz(w6); w6 &= w6 - 1; A[6] += wp[i * 64]; }
                if (w7) { int i = __builtin_ctz(w7); w7 &= w7 - 1; A[7] += wp[i * 64]; }
            }
        }
    }
    float y[8];
    y[0] = A[0];
    y[1] = A[0] + A[1];
    y[2] = A[0] + A[2];
    y[3] = A[0] + A[1] + A[3];
    y[4] = A[0] + A[4];
    y[5] = A[0] + A[1] + A[2] + A[5];
    y[6] = A[0] + A[6];
    y[7] = A[0] + A[1] + A[3] + A[7];
    float bo = b2[lane];
    uint32_t mout = 0;
    float v = 0.f;
    #pragma unroll
    for (int t = 0; t < 8; t++) {
        float yt = y[t] + bo;
        v = v + (yt - v) * 0.5f;
        bool sp = (v >= 1.0f);
        mout |= sp ? (1u << t) : 0u;
        v = sp ? 0.f : v;
    }
    unsigned long long* op = (unsigned long long*)(s2p + (size_t)(b * P2 + pix) * 64);
    #pragma unroll
    for (int t = 0; t < 8; t++) {
        unsigned long long bm = __ballot((mout >> t) & 1u);
        if (lane == 0) op[t] = bm;
    }
}

// ---------------- conv3 + LIF3 (guarded 8-chain scan, round-13) ----------
__global__ __launch_bounds__(256) void k_conv3(const uint8_t* __restrict__ s2p,
                                               const float* __restrict__ w3T,
                                               const float* __restrict__ b3,
                                               uint8_t* __restrict__ s3m) {
    int wid = blockIdx.x * 4 + (threadIdx.x >> 6);
    int lane = threadIdx.x & 63;
    int b = wid / P3, pix = wid - b * P3;
    int oy = pix / W3, ox = pix - oy * W3;
    float A[8];
    #pragma unroll
    for (int t = 0; t < 8; t++) A[t] = 0.f;
    #pragma unroll
    for (int ky = 0; ky < 3; ky++) {
        #pragma unroll
        for (int kx = 0; kx < 3; kx++) {
            int mofs = RFL((b * P2 + (oy + ky) * W2 + (ox + kx)) * 64);
            const unsigned long long* mp = (const unsigned long long*)(s2p + mofs);
            const float* wp = w3T + (ky * 3 + kx) * 64 * 64 + lane;
            unsigned long long m0 = mp[0], m1 = mp[1], m2 = mp[2], m3 = mp[3];
            unsigned long long m4 = mp[4], m5 = mp[5], m6 = mp[6], m7 = mp[7];
            while (m0 | m1 | m2 | m3 | m4 | m5 | m6 | m7) {
                if (m0) { int i = __builtin_ctzll(m0); m0 &= m0 - 1; A[0] += wp[i * 64]; }
                if (m1) { int i = __builtin_ctzll(m1); m1 &= m1 - 1; A[1] += wp[i * 64]; }
                if (m2) { int i = __builtin_ctzll(m2); m2 &= m2 - 1; A[2] += wp[i * 64]; }
                if (m3) { int i = __builtin_ctzll(m3); m3 &= m3 - 1; A[3] += wp[i * 64]; }
                if (m4) { int i = __builtin_ctzll(m4); m4 &= m4 - 1; A[4] += wp[i * 64]; }
                if (m5) { int i = __builtin_ctzll(m5); m5 &= m5 - 1; A[5] += wp[i * 64]; }
                if (m6) { int i = __builtin_ctzll(m6); m6 &= m6 - 1; A[6] += wp[i * 64]; }
                if (m7) { int i = __builtin_ctzll(m7); m7 &= m7 - 1; A[7] += wp[i * 64]; }
            }
        }
    }
    float bo = b3[lane];
    uint32_t mout = 0;
    float v = 0.f;
    #pragma unroll
    for (int t = 0; t < 8; t++) {
        float y = A[t] + bo;
        v = v + (y - v) * 0.5f;
        bool sp = (v >= 1.0f);
        mout |= sp ? (1u << t) : 0u;
        v = sp ? 0.f : v;
    }
    s3m[(size_t)(b * P3 + pix) * 64 + lane] = (uint8_t)mout;
}

// ---------------- fc1 + LIF4 + mean + fc2 ----------------
__global__ __launch_bounds__(256) void k_fc(const uint8_t* __restrict__ s3m,
                                            const float* __restrict__ fw1T,
                                            const float* __restrict__ fb1,
                                            const float* __restrict__ fw2,
                                            const float* __restrict__ fb2,
                                            float* __restrict__ out) {
    __shared__ float red[3][64][65];
    int b = blockIdx.x;
    int w = threadIdx.x >> 6;
    int lane = threadIdx.x & 63;
    float acc[8][8];
    #pragma unroll
    for (int j = 0; j < 8; j++)
        #pragma unroll
        for (int t = 0; t < 8; t++) acc[j][t] = 0.f;

    int ibeg = w * 784;
    for (int i0 = ibeg; i0 < ibeg + 784; i0 += 16) {
        int base = RFL(b * K + i0);
        const uint32_t* mp = (const uint32_t*)(s3m + base);
        #pragma unroll
        for (int d = 0; d < 4; d++) {
            uint32_t md = mp[d];
            if (md == 0) continue;
            #pragma unroll
            for (int q = 0; q < 4; q++) {
                uint32_t m = (md >> (q * 8)) & 0xffu;
                if (m == 0) continue;
                int i_our = i0 + d * 4 + q;
                int pix = i_our >> 6, c = i_our & 63;
                const float4* wp = (const float4*)(fw1T + (size_t)(c * 49 + pix) * O + lane * 8);
                float4 wa = wp[0], wb = wp[1];
                float wv[8] = {wa.x, wa.y, wa.z, wa.w, wb.x, wb.y, wb.z, wb.w};
                #pragma unroll
                for (int t = 0; t < 8; t++) {
                    if (m & (1u << t)) {
                        #pragma unroll
                        for (int j = 0; j < 8; j++) acc[j][t] += wv[j];
                    }
                }
            }
        }
    }

    if (w > 0) {
        #pragma unroll
        for (int j = 0; j < 8; j++)
            #pragma unroll
            for (int t = 0; t < 8; t++) red[w - 1][lane][j * 8 + t] = acc[j][t];
    }
    __syncthreads();
    if (w != 0) return;

    #pragma unroll
    for (int ww = 0; ww < 3; ww++)
        #pragma unroll
        for (int j = 0; j < 8; j++)
            #pragma unroll
            for (int t = 0; t < 8; t++) acc[j][t] += red[ww][lane][j * 8 + t];

    float msum[8];
    #pragma unroll
    for (int j = 0; j < 8; j++) {
        float yb = fb1[lane * 8 + j];
        float v = 0.f, cntt = 0.f;
        #pragma unroll
        for (int t = 0; t < 8; t++) {
            float y = acc[j][t] + yb;
            v = v + (y - v) * 0.5f;
            bool sp = (v >= 1.0f);
            cntt += sp ? 1.f : 0.f;
            v = sp ? 0.f : v;
        }
        msum[j] = cntt * 0.125f;
    }
    #pragma unroll
    for (int kk = 0; kk < 6; kk++) {
        const float* wr = fw2 + kk * O + lane * 8;
        float pv = 0.f;
        #pragma unroll
        for (int j = 0; j < 8; j++) pv += msum[j] * wr[j];
        #pragma unroll
        for (int off = 32; off > 0; off >>= 1) pv += __shfl_down(pv, off, 64);
        if (lane == 0) out[b * 6 + kk] = pv + fb2[kk];
    }
}

// ---------------- launch ----------------
extern "C" void kernel_launch(void* const* d_in, const int* in_sizes, int n_in,
                              void* d_out, int out_size, void* d_ws, size_t ws_size,
                              hipStream_t stream) {
    const float* x   = (const float*)d_in[0];
    const float* w1  = (const float*)d_in[1];
    const float* b1  = (const float*)d_in[2];
    const float* w2  = (const float*)d_in[3];
    const float* b2  = (const float*)d_in[4];
    const float* w3  = (const float*)d_in[5];
    const float* b3  = (const float*)d_in[6];
    const float* fw1 = (const float*)d_in[7];
    const float* fb1 = (const float*)d_in[8];
    const float* fw2 = (const float*)d_in[9];
    const float* fb2 = (const float*)d_in[10];
    float* out = (float*)d_out;

    uint8_t*  ws   = (uint8_t*)d_ws;
    uint8_t*  s1c  = ws + OFF_S1;
    uint8_t*  s2p  = ws + OFF_S2;
    uint8_t*  s3m  = ws + OFF_S3;
    float*    w2T  = (float*)(ws + OFF_W2T);
    float*    w3T  = (float*)(ws + OFF_W3T);
    float*    fw1T = (float*)(ws + OFF_FW1T);
    float*    w1T  = (float*)(ws + OFF_W1T);
    uint32_t* cnt  = (uint32_t*)(ws + OFF_CNT);
    uint16_t* evl  = (uint16_t*)(ws + OFF_EVT);

    // 8192 + 32832 + 36864 = 77888 -> 305 blocks
    hipLaunchKernelGGL(k_prep_all, dim3(305),   dim3(256), 0, stream,
                       w1, w1T, w2, w2T, w3, w3T);
    hipLaunchKernelGGL(k_prep_fw1, dim3(392),   dim3(256), 0, stream, fw1, fw1T);
    hipLaunchKernelGGL(k_conv1,    dim3(1600),  dim3(256), 0, stream, x, w1T, b1, s1c);
    if (ws_size >= WS_NEEDED) {
        hipLaunchKernelGGL(k_evt,      dim3(1296),  dim3(256), 0, stream, s1c, cnt, evl);
        hipLaunchKernelGGL(k_conv2_ev, dim3(10368), dim3(256), 0, stream, cnt, evl, w2T, b2, s2p);
    } else {
        hipLaunchKernelGGL(k_conv2_old, dim3(10368), dim3(256), 0, stream, s1c, w2T, b2, s2p);
    }
    hipLaunchKernelGGL(k_conv3,    dim3(6272),  dim3(256), 0, stream, s2p, w3T, b3, s3m);
    hipLaunchKernelGGL(k_fc,       dim3(512),   dim3(256), 0, stream, s3m, fw1T, fb1, fw2, fb2, out);
}